// Round 1
// baseline (188.408 us; speedup 1.0000x reference)
//
#include <hip/hip_runtime.h>
#include <stdint.h>

typedef unsigned long long u64;
typedef unsigned int u32;

#define NC 80
#define CONF_T 0.25f
#define IOU_THR 0.45f
#define MAX_DET 300
#define KCAND 1024
#define A_ANCH 8400
#define NROWS 84
#define MAX_WH 7680.0f

// Kernel 1: per-anchor class max/argmax -> packed sort key into ws.
// key = (score_bits << 32) | ((16383 - anchor) << 7) | cls
// Descending u64 order == descending score, ties by ascending anchor index
// (matches jax.lax.top_k tie-breaking).
__global__ void yolo_conf_kernel(const float* __restrict__ preds, u64* __restrict__ keys) {
    int bid = blockIdx.x;
    int b = bid / 33;
    int chunk = bid % 33;
    int a = chunk * 256 + threadIdx.x;
    if (a >= A_ANCH) return;
    const float* base = preds + ((size_t)b * NROWS + 4) * A_ANCH + a;
    float best = base[0];
    int bestc = 0;
#pragma unroll 4
    for (int c = 1; c < NC; ++c) {
        float v = base[(size_t)c * A_ANCH];
        if (v > best) { best = v; bestc = c; }   // strict > keeps first max (argmax semantics)
    }
    float score = (best > CONF_T) ? best : 0.0f;
    u32 bits = __float_as_uint(score);           // score >= 0 -> monotonic as uint
    u64 key = ((u64)bits << 32) | ((u64)(16383 - a) << 7) | (u64)bestc;
    keys[(size_t)b * A_ANCH + a] = key;
}

// Kernel 2: per-batch top-1024 select (radix) + bitonic sort + greedy NMS + output.
__global__ __launch_bounds__(1024) void yolo_nms_kernel(const float* __restrict__ preds,
                                                        const u64* __restrict__ keys,
                                                        float* __restrict__ out) {
    const int b = blockIdx.x;
    const int tid = threadIdx.x;
    const int lane = tid & 63;
    const int wid = tid >> 6;

    __shared__ u32 sc[A_ANCH];        // 33600 B; reused later for box arrays
    __shared__ u64 skey[KCAND];       // 8192 B
    __shared__ u32 hist[256];
    __shared__ u32 eqw[264];
    __shared__ u32 wpre[264];
    __shared__ int rankmap[MAX_DET];
    __shared__ u64 s_keepm;
    __shared__ u32 s_scal[4];         // 0: radix prefix, 1: k-remaining, 2: compact count, 3: kept total
    __shared__ u32 wave_tot[16];

    const u64* kb = keys + (size_t)b * A_ANCH;
    for (int a = tid; a < A_ANCH; a += 1024) sc[a] = (u32)(kb[a] >> 32);
    if (tid == 0) { s_scal[0] = 0; s_scal[1] = KCAND; s_scal[2] = 0; s_scal[3] = 0; }
    __syncthreads();

    // ---- radix select: P = 1024th-largest score bits ----
    for (int p = 0; p < 4; ++p) {
        int shift = 24 - 8 * p;
        if (tid < 256) hist[tid] = 0;
        __syncthreads();
        u32 prefix = s_scal[0];
        for (int a = tid; a < A_ANCH; a += 1024) {
            u32 v = sc[a];
            bool m;
            if (p == 0) m = true;
            else m = ((v >> (shift + 8)) == prefix);
            if (m) atomicAdd(&hist[(v >> shift) & 255u], 1u);
        }
        __syncthreads();
        if (tid == 0) {
            u32 rem = s_scal[1];
            int chosen = 0;
            for (int d = 255; d >= 0; --d) {
                u32 c = hist[d];
                if (rem <= c) { chosen = d; break; }
                rem -= c;
            }
            s_scal[0] = (prefix << 8) | (u32)chosen;
            s_scal[1] = rem;
        }
        __syncthreads();
    }
    const u32 P = s_scal[0];
    const u32 tEq = s_scal[1];   // take tEq lowest-index elements among score==P

    // ---- equality bitmask + word prefix (tie handling) ----
    if (tid < 264) eqw[tid] = 0;
    __syncthreads();
    for (int a = tid; a < A_ANCH; a += 1024)
        if (sc[a] == P) atomicOr(&eqw[a >> 5], 1u << (a & 31));
    __syncthreads();
    if (tid == 0) {
        u32 run = 0;
        for (int w2 = 0; w2 < 264; ++w2) { wpre[w2] = run; run += __popc(eqw[w2]); }
    }
    __syncthreads();

    // ---- compaction of exactly 1024 selected keys ----
    for (int a = tid; a < A_ANCH; a += 1024) {
        u32 v = sc[a];
        bool take = v > P;
        if (!take && v == P) {
            u32 r = wpre[a >> 5] + __popc(eqw[a >> 5] & ((1u << (a & 31)) - 1u));
            take = (r < tEq);
        }
        if (take) {
            u32 pos = atomicAdd(&s_scal[2], 1u);
            skey[pos] = kb[a];
        }
    }
    __syncthreads();

    // ---- bitonic sort, descending (keys unique -> deterministic) ----
    for (u32 size = 2; size <= KCAND; size <<= 1) {
        for (u32 stride = size >> 1; stride >= 1; stride >>= 1) {
            __syncthreads();
            if (tid < KCAND / 2) {
                u32 i1 = ((u32)(tid & ~(int)(stride - 1)) << 1) | ((u32)tid & (stride - 1));
                u32 i2 = i1 + stride;
                bool descSeg = ((i1 & size) == 0);
                u64 x = skey[i1], y = skey[i2];
                if ((x < y) == descSeg) { skey[i1] = y; skey[i2] = x; }
            }
        }
    }
    __syncthreads();

    // ---- per-candidate offset boxes (overlay onto sc region) ----
    float* BX1 = (float*)sc;
    float* BY1 = BX1 + KCAND;
    float* BX2 = BX1 + 2 * KCAND;
    float* BY2 = BX1 + 3 * KCAND;
    float* BAR = BX1 + 4 * KCAND;
    u32* SUPP = (u32*)(BX1 + 5 * KCAND);
    u32* KEEP = (u32*)(BX1 + 6 * KCAND);
    {
        u64 key = skey[tid];
        int cls = (int)(key & 127u);
        int idx = 16383 - (int)((key >> 7) & 16383u);
        const float* pb = preds + (size_t)b * NROWS * A_ANCH + idx;
        float x = pb[0];
        float y = pb[A_ANCH];
        float w = pb[2 * A_ANCH];
        float h = pb[3 * A_ANCH];
        float hw = __fmul_rn(w, 0.5f), hh = __fmul_rn(h, 0.5f);
        float x1 = __fsub_rn(x, hw), x2 = __fadd_rn(x, hw);
        float y1 = __fsub_rn(y, hh), y2 = __fadd_rn(y, hh);
        float off = __fmul_rn((float)cls, MAX_WH);
        float bx1 = __fadd_rn(x1, off), bx2 = __fadd_rn(x2, off);
        float by1 = __fadd_rn(y1, off), by2 = __fadd_rn(y2, off);
        BX1[tid] = bx1; BY1[tid] = by1; BX2[tid] = bx2; BY2[tid] = by2;
        // area from OFFSET coords, exactly as reference _box_iou does
        BAR[tid] = __fmul_rn(__fsub_rn(bx2, bx1), __fsub_rn(by2, by1));
        SUPP[tid] = 0; KEEP[tid] = 0;
    }
    __syncthreads();

    // ---- greedy NMS: 16 chunks of 64, wave-serial within chunk ----
    for (int c = 0; c < KCAND / 64; ++c) {
        if (wid == 0) {
            int j = c * 64 + lane;
            u64 keyj = skey[j];
            float scj = __uint_as_float((u32)(keyj >> 32));
            bool validj = scj > CONF_T;
            bool suppj = SUPP[j] != 0;
            float mx1 = BX1[j], my1 = BY1[j], mx2 = BX2[j], my2 = BY2[j], mar = BAR[j];
            u64 alive = __ballot(validj && !suppj);
            u64 keepm = 0;
            while (alive) {
                int i = __ffsll((unsigned long long)alive) - 1;
                keepm |= (1ull << i);
                int ji = c * 64 + i;
                float ix1 = BX1[ji], iy1 = BY1[ji], ix2 = BX2[ji], iy2 = BY2[ji], iar = BAR[ji];
                float lx = fmaxf(ix1, mx1), ly = fmaxf(iy1, my1);
                float rx = fminf(ix2, mx2), ry = fminf(iy2, my2);
                float ww = fmaxf(__fsub_rn(rx, lx), 0.0f);
                float hh2 = fmaxf(__fsub_rn(ry, ly), 0.0f);
                float inter = __fmul_rn(ww, hh2);
                float den = __fadd_rn(__fsub_rn(__fadd_rn(iar, mar), inter), 1e-7f);
                float iou = __fdiv_rn(inter, den);
                bool s = (iou > IOU_THR) && (lane > i);
                u64 sm = __ballot(s);
                alive &= ~(sm | (1ull << i));
            }
            KEEP[j] = (u32)((keepm >> lane) & 1ull);
            if (lane == 0) { s_keepm = keepm; atomicAdd(&s_scal[3], (u32)__popcll(keepm)); }
        }
        __syncthreads();
        // suppress later chunks by this chunk's kept set
        u64 km = s_keepm;
        int j = tid;
        if (j >= (c + 1) * 64 && km && SUPP[j] == 0) {
            float mx1 = BX1[j], my1 = BY1[j], mx2 = BX2[j], my2 = BY2[j], mar = BAR[j];
            u64 mm = km;
            while (mm) {
                int i = __ffsll((unsigned long long)mm) - 1;
                mm &= mm - 1;
                int ji = c * 64 + i;
                float ix1 = BX1[ji], iy1 = BY1[ji], ix2 = BX2[ji], iy2 = BY2[ji], iar = BAR[ji];
                float lx = fmaxf(ix1, mx1), ly = fmaxf(iy1, my1);
                float rx = fminf(ix2, mx2), ry = fminf(iy2, my2);
                float ww = fmaxf(__fsub_rn(rx, lx), 0.0f);
                float hh2 = fmaxf(__fsub_rn(ry, ly), 0.0f);
                float inter = __fmul_rn(ww, hh2);
                float den = __fadd_rn(__fsub_rn(__fadd_rn(iar, mar), inter), 1e-7f);
                float iou = __fdiv_rn(inter, den);
                if (iou > IOU_THR) { SUPP[j] = 1; break; }
            }
        }
        __syncthreads();
        if (s_scal[3] >= MAX_DET) break;   // first 300 kept already determined
    }

    // ---- rank kept candidates, build rank -> candidate map ----
    bool mk = KEEP[tid] != 0;
    u64 wm = __ballot(mk);
    if (lane == 0) wave_tot[wid] = (u32)__popcll(wm);
    if (tid < MAX_DET) rankmap[tid] = -1;
    __syncthreads();
    u32 basecnt = 0;
    for (int w2 = 0; w2 < wid; ++w2) basecnt += wave_tot[w2];
    u32 rank = basecnt + (u32)__popcll(wm & ((1ull << lane) - 1ull));
    if (mk && rank < MAX_DET) rankmap[rank] = tid;
    __syncthreads();

    // ---- emit output rows ----
    if (tid < MAX_DET) {
        float row[6];
        int t = rankmap[tid];
        if (t >= 0) {
            u64 key = skey[t];
            u32 bits = (u32)(key >> 32);
            float score = __uint_as_float(bits);
            int cls = (int)(key & 127u);
            int idx = 16383 - (int)((key >> 7) & 16383u);
            const float* pb = preds + (size_t)b * NROWS * A_ANCH + idx;
            float x = pb[0], y = pb[A_ANCH], w = pb[2 * A_ANCH], h = pb[3 * A_ANCH];
            float hw = __fmul_rn(w, 0.5f), hh = __fmul_rn(h, 0.5f);
            row[0] = __fsub_rn(x, hw);
            row[1] = __fsub_rn(y, hh);
            row[2] = __fadd_rn(x, hw);
            row[3] = __fadd_rn(y, hh);
            row[4] = score;
            row[5] = (float)cls;
        } else {
            row[0] = row[1] = row[2] = row[3] = row[4] = row[5] = (float)NC;
        }
        float* o = out + ((size_t)b * MAX_DET + tid) * 6;
#pragma unroll
        for (int q = 0; q < 6; ++q) o[q] = row[q];
    }
}

extern "C" void kernel_launch(void* const* d_in, const int* in_sizes, int n_in,
                              void* d_out, int out_size, void* d_ws, size_t ws_size,
                              hipStream_t stream) {
    const float* preds = (const float*)d_in[0];
    float* out = (float*)d_out;
    u64* keys = (u64*)d_ws;   // B * 8400 * 8 bytes = ~2.1 MB
    int B = in_sizes[0] / (NROWS * A_ANCH);
    dim3 g1(B * ((A_ANCH + 255) / 256));
    yolo_conf_kernel<<<g1, dim3(256), 0, stream>>>(preds, keys);
    yolo_nms_kernel<<<dim3(B), dim3(1024), 0, stream>>>(preds, keys, out);
}

// Round 2
// 80.440 us; speedup vs baseline: 2.3422x; 2.3422x over previous
//
#include <hip/hip_runtime.h>
#include <stdint.h>

typedef unsigned long long u64;
typedef unsigned int u32;

#define NC 80
#define CONF_T 0.25f
#define IOU_THR 0.45f
#define MAX_DET 300
#define KCAND 1024
#define A_ANCH 8400
#define NROWS 84
#define MAX_WH 7680.0f

// ---------------- Kernel 1: per-anchor class max/argmax -> packed sort key ----------------
// key = (score_bits << 32) | ((16383 - anchor) << 7) | cls
// Descending u64 == descending score, ties by ascending anchor (top_k tie-break).
__global__ void yolo_conf_kernel(const float* __restrict__ preds, u64* __restrict__ keys) {
    int b = blockIdx.x / 9;
    int chunk = blockIdx.x % 9;
    int g = chunk * 256 + threadIdx.x;          // anchor group (4 anchors each)
    if (g >= A_ANCH / 4) return;
    int a0 = g * 4;
    const float* base = preds + ((size_t)b * NROWS + 4) * A_ANCH + a0;
    float4 best = *(const float4*)base;
    int bcx = 0, bcy = 0, bcz = 0, bcw = 0;
#pragma unroll 4
    for (int c = 1; c < NC; ++c) {
        float4 v = *(const float4*)(base + (size_t)c * A_ANCH);
        if (v.x > best.x) { best.x = v.x; bcx = c; }
        if (v.y > best.y) { best.y = v.y; bcy = c; }
        if (v.z > best.z) { best.z = v.z; bcz = c; }
        if (v.w > best.w) { best.w = v.w; bcw = c; }
    }
    u64* ko = keys + (size_t)b * A_ANCH + a0;
    float bs[4] = {best.x, best.y, best.z, best.w};
    int bc[4] = {bcx, bcy, bcz, bcw};
#pragma unroll
    for (int q = 0; q < 4; ++q) {
        float score = (bs[q] > CONF_T) ? bs[q] : 0.0f;
        u32 bits = __float_as_uint(score);
        ko[q] = ((u64)bits << 32) | ((u64)(16383 - (a0 + q)) << 7) | (u64)bc[q];
    }
}

__device__ __forceinline__ float iou_f(float ix1, float iy1, float ix2, float iy2, float iar,
                                       float jx1, float jy1, float jx2, float jy2, float jar) {
    float lx = fmaxf(ix1, jx1), ly = fmaxf(iy1, jy1);
    float rx = fminf(ix2, jx2), ry = fminf(iy2, jy2);
    float ww = fmaxf(__fsub_rn(rx, lx), 0.0f);
    float hh = fmaxf(__fsub_rn(ry, ly), 0.0f);
    float inter = __fmul_rn(ww, hh);
    float den = __fadd_rn(__fsub_rn(__fadd_rn(iar, jar), inter), 1e-7f);
    return __fdiv_rn(inter, den);
}

// ---------------- Kernel 2: top-1024 select + sort + greedy NMS + emit ----------------
__global__ __launch_bounds__(1024) void yolo_nms_kernel(const float* __restrict__ preds,
                                                        const u64* __restrict__ keys,
                                                        float* __restrict__ out) {
    const int b = blockIdx.x;
    const int tid = threadIdx.x;
    const int lane = tid & 63;
    const int wid = tid >> 6;

    __shared__ u32 sc[A_ANCH];              // 33600 B; later overlaid with box arrays
    __shared__ u64 skey[KCAND];             // 8192 B
    __shared__ u32 histw[16][256];          // 16384 B, per-wave privatized histograms
    __shared__ u32 hist[256];               // 1024 B, reduced histogram
    __shared__ union {
        struct { u32 eqw[264]; u32 wpre[264]; } pre;       // tie handling (before sort)
        struct { u64 rows[64]; int keptlist[384]; } post;  // NMS state (after sort)
    } ov;
    __shared__ u32 s_scal[4];               // 0: radix prefix, 1: k-remaining, 2: compact cnt
    __shared__ u32 s_csupp[2];              // current-chunk suppression mask (lo/hi)
    __shared__ u32 s_nkept;

    const u64* kb = keys + (size_t)b * A_ANCH;
    for (int a = tid; a < A_ANCH; a += 1024) sc[a] = (u32)(kb[a] >> 32);
    if (tid == 0) { s_scal[0] = 0; s_scal[1] = KCAND; s_scal[2] = 0; s_csupp[0] = 0; s_csupp[1] = 0; s_nkept = 0; }
    __syncthreads();

    // ---- radix select: P = 1024th-largest score bits ----
    for (int p = 0; p < 4; ++p) {
        int shift = 24 - 8 * p;
        u32* hwf = &histw[0][0];
        for (int i = tid; i < 16 * 256; i += 1024) hwf[i] = 0;
        __syncthreads();
        u32 prefix = s_scal[0];
#pragma unroll
        for (int it = 0; it < 9; ++it) {
            int a = tid + it * 1024;
            u32 v = 0, bin = 0;
            bool m = false;
            if (a < A_ANCH) {
                v = sc[a];
                m = (p == 0) || ((v >> (shift + 8)) == prefix);
                bin = (v >> shift) & 255u;
            }
            u64 actm = __ballot(m);
            if (actm) {
                int fl = __ffsll(actm) - 1;
                u32 fb = __shfl(bin, fl);
                if (__ballot(m && (bin != fb)) == 0ull) {
                    // wave-uniform bin fast path: one atomic per wave
                    if (lane == fl) atomicAdd(&histw[wid][fb], (u32)__popcll(actm));
                } else if (m) {
                    atomicAdd(&histw[wid][bin], 1u);
                }
            }
        }
        __syncthreads();
        if (tid < 256) {
            u32 s = 0;
#pragma unroll
            for (int w = 0; w < 16; ++w) s += histw[w][tid];
            hist[tid] = s;
        }
        __syncthreads();
        if (wid == 0) {
            // suffix-select via wave prefix scan over descending bins; lane l covers d=255-4l..252-4l
            u32 g[4], loc = 0;
#pragma unroll
            for (int q = 0; q < 4; ++q) { g[q] = hist[255 - (lane * 4 + q)]; loc += g[q]; }
            u32 pre = loc;
#pragma unroll
            for (int off = 1; off < 64; off <<= 1) {
                u32 o = __shfl_up(pre, off);
                if (lane >= off) pre += o;
            }
            u32 run = pre - loc;                 // elements in bins above this lane's range
            u32 rem = s_scal[1];
            u32 pfx = s_scal[0];
#pragma unroll
            for (int q = 0; q < 4; ++q) {
                int d = 255 - (lane * 4 + q);
                if (run < rem && rem <= run + g[q]) {
                    s_scal[0] = (pfx << 8) | (u32)d;
                    s_scal[1] = rem - run;
                }
                run += g[q];
            }
        }
        __syncthreads();
    }
    const u32 P = s_scal[0];
    const u32 tEq = s_scal[1];      // take tEq lowest-index elements among score==P

    // ---- tie handling: bitmask of score==P + parallel word-prefix ----
    if (tid < 264) ov.pre.eqw[tid] = 0;
    __syncthreads();
    for (int a = tid; a < A_ANCH; a += 1024)
        if (sc[a] == P) atomicOr(&ov.pre.eqw[a >> 5], 1u << (a & 31));
    __syncthreads();
    if (wid == 0) {
        u32 cnt[5], loc = 0;
#pragma unroll
        for (int q = 0; q < 5; ++q) {
            int w2 = lane * 5 + q;
            u32 e = (w2 < 264) ? ov.pre.eqw[w2] : 0u;
            cnt[q] = (u32)__popc(e); loc += cnt[q];
        }
        u32 pre = loc;
#pragma unroll
        for (int off = 1; off < 64; off <<= 1) {
            u32 o = __shfl_up(pre, off);
            if (lane >= off) pre += o;
        }
        u32 run = pre - loc;
#pragma unroll
        for (int q = 0; q < 5; ++q) {
            int w2 = lane * 5 + q;
            if (w2 < 264) ov.pre.wpre[w2] = run;
            run += cnt[q];
        }
    }
    __syncthreads();

    // ---- compaction of exactly 1024 selected keys ----
    for (int a = tid; a < A_ANCH; a += 1024) {
        u32 v = sc[a];
        bool take = v > P;
        if (!take && v == P) {
            u32 r = ov.pre.wpre[a >> 5] + (u32)__popc(ov.pre.eqw[a >> 5] & ((1u << (a & 31)) - 1u));
            take = (r < tEq);
        }
        if (take) {
            u32 pos = atomicAdd(&s_scal[2], 1u);
            skey[pos] = kb[a];
        }
    }
    __syncthreads();

    // ---- bitonic sort, descending (keys unique -> deterministic) ----
    for (u32 size = 2; size <= KCAND; size <<= 1) {
        for (u32 stride = size >> 1; stride >= 1; stride >>= 1) {
            __syncthreads();
            if (tid < KCAND / 2) {
                u32 i1 = ((u32)(tid & ~(int)(stride - 1)) << 1) | ((u32)tid & (stride - 1));
                u32 i2 = i1 + stride;
                bool descSeg = ((i1 & size) == 0);
                u64 x = skey[i1], y = skey[i2];
                if ((x < y) == descSeg) { skey[i1] = y; skey[i2] = x; }
            }
        }
    }
    __syncthreads();

    // ---- per-candidate offset boxes (overlay onto sc region) ----
    float* BX1 = (float*)sc;
    float* BY1 = BX1 + KCAND;
    float* BX2 = BX1 + 2 * KCAND;
    float* BY2 = BX1 + 3 * KCAND;
    float* BAR = BX1 + 4 * KCAND;
    {
        u64 key = skey[tid];
        int cls = (int)(key & 127u);
        int idx = 16383 - (int)((key >> 7) & 16383u);
        const float* pb = preds + (size_t)b * NROWS * A_ANCH + idx;
        float x = pb[0];
        float y = pb[A_ANCH];
        float w = pb[2 * A_ANCH];
        float h = pb[3 * A_ANCH];
        float hw = __fmul_rn(w, 0.5f), hh = __fmul_rn(h, 0.5f);
        float x1 = __fsub_rn(x, hw), x2 = __fadd_rn(x, hw);
        float y1 = __fsub_rn(y, hh), y2 = __fadd_rn(y, hh);
        float off = __fmul_rn((float)cls, MAX_WH);
        float bx1 = __fadd_rn(x1, off), bx2 = __fadd_rn(x2, off);
        float by1 = __fadd_rn(y1, off), by2 = __fadd_rn(y2, off);
        BX1[tid] = bx1; BY1[tid] = by1; BX2[tid] = bx2; BY2[tid] = by2;
        BAR[tid] = __fmul_rn(__fsub_rn(bx2, bx1), __fsub_rn(by2, by1));  // area of OFFSET box, as reference
    }
    __syncthreads();

    // ---- greedy NMS: 16 chunks of 64 ----
    for (int c = 0; c < KCAND / 64; ++c) {
        int j = c * 64 + lane;
        u64 keyj = skey[j];
        float scj = __uint_as_float((u32)(keyj >> 32));
        float jx1 = BX1[j], jy1 = BY1[j], jx2 = BX2[j], jy2 = BY2[j], jar = BAR[j];

        // Phase A: suppress this chunk's 64 candidates vs compact kept list (parallel over waves)
        u32 nk = s_nkept;
        u32 suppbit = 0;
        for (u32 k = wid; k < nk; k += 16) {
            int i = ov.post.keptlist[k];
            if (iou_f(BX1[i], BY1[i], BX2[i], BY2[i], BAR[i], jx1, jy1, jx2, jy2, jar) > IOU_THR) {
                suppbit = 1; break;
            }
        }
        u64 bm = __ballot(suppbit != 0);
        if (lane == 0 && bm) {
            atomicOr(&s_csupp[0], (u32)bm);
            atomicOr(&s_csupp[1], (u32)(bm >> 32));
        }

        // Phase B: in-chunk 64x64 suppression matrix, one row per wave per pass
#pragma unroll
        for (int p2 = 0; p2 < 4; ++p2) {
            int i = p2 * 16 + wid;
            int ci = c * 64 + i;
            float iou = iou_f(BX1[ci], BY1[ci], BX2[ci], BY2[ci], BAR[ci], jx1, jy1, jx2, jy2, jar);
            u64 m = __ballot((lane > i) && (iou > IOU_THR));
            if (lane == 0) ov.post.rows[i] = m;
        }
        __syncthreads();

        // Phase C: wave-0 uniform greedy recurrence over 64 bits
        if (wid == 0) {
            u64 row = ov.post.rows[lane];
            u64 csupp = (((u64)s_csupp[1]) << 32) | (u64)s_csupp[0];
            u64 valid = __ballot(scj > CONF_T) & ~csupp;
            u32 rlo = (u32)row, rhi = (u32)(row >> 32);
            u64 supp = 0, keep = 0;
#pragma unroll
            for (int i = 0; i < 64; ++i) {
                u64 ri = (((u64)__shfl(rhi, i)) << 32) | (u64)__shfl(rlo, i);
                bool ki = (((valid & ~supp) >> i) & 1ull) != 0;
                if (ki) { keep |= (1ull << i); supp |= ri; }
            }
            u32 base = s_nkept;
            if ((keep >> lane) & 1ull) {
                u32 r = (u32)__popcll(keep & ((1ull << lane) - 1ull));
                ov.post.keptlist[base + r] = j;
            }
            if (lane == 0) {
                s_nkept = base + (u32)__popcll(keep);
                s_csupp[0] = 0; s_csupp[1] = 0;
            }
        }
        __syncthreads();
        if (s_nkept >= MAX_DET) break;   // suppression flows only forward; first 300 fixed
    }

    // ---- emit output rows ----
    if (tid < MAX_DET) {
        u32 nk = s_nkept;
        float row[6];
        int t = (tid < (int)(nk < MAX_DET ? nk : MAX_DET)) ? ov.post.keptlist[tid] : -1;
        if (t >= 0) {
            u64 key = skey[t];
            u32 bits = (u32)(key >> 32);
            float score = __uint_as_float(bits);
            int cls = (int)(key & 127u);
            int idx = 16383 - (int)((key >> 7) & 16383u);
            const float* pb = preds + (size_t)b * NROWS * A_ANCH + idx;
            float x = pb[0], y = pb[A_ANCH], w = pb[2 * A_ANCH], h = pb[3 * A_ANCH];
            float hw = __fmul_rn(w, 0.5f), hh = __fmul_rn(h, 0.5f);
            row[0] = __fsub_rn(x, hw);
            row[1] = __fsub_rn(y, hh);
            row[2] = __fadd_rn(x, hw);
            row[3] = __fadd_rn(y, hh);
            row[4] = score;
            row[5] = (float)cls;
        } else {
            row[0] = row[1] = row[2] = row[3] = row[4] = row[5] = (float)NC;
        }
        float* o = out + ((size_t)b * MAX_DET + tid) * 6;
#pragma unroll
        for (int q = 0; q < 6; ++q) o[q] = row[q];
    }
}

extern "C" void kernel_launch(void* const* d_in, const int* in_sizes, int n_in,
                              void* d_out, int out_size, void* d_ws, size_t ws_size,
                              hipStream_t stream) {
    const float* preds = (const float*)d_in[0];
    float* out = (float*)d_out;
    u64* keys = (u64*)d_ws;   // B * 8400 * 8 bytes ~= 2.1 MB
    int B = in_sizes[0] / (NROWS * A_ANCH);
    yolo_conf_kernel<<<dim3(B * 9), dim3(256), 0, stream>>>(preds, keys);
    yolo_nms_kernel<<<dim3(B), dim3(1024), 0, stream>>>(preds, keys, out);
}

// Round 3
// 79.151 us; speedup vs baseline: 2.3804x; 1.0163x over previous
//
#include <hip/hip_runtime.h>
#include <stdint.h>

typedef unsigned long long u64;
typedef unsigned int u32;

#define NC 80
#define CONF_T 0.25f
#define IOU_THR 0.45f
#define MAX_DET 300
#define KCAND 1024
#define A_ANCH 8400
#define NROWS 84
#define MAX_WH 7680.0f

// ---------------- Kernel 1: per-anchor class max/argmax -> packed sort key ----------------
// key = (score_bits << 32) | ((16383 - anchor) << 7) | cls
__global__ __launch_bounds__(512) void yolo_conf_kernel(const float* __restrict__ preds,
                                                        u64* __restrict__ keys) {
    int b = blockIdx.x / 9;
    int g = (blockIdx.x % 9) * 512 + threadIdx.x;    // float2 group
    if (g >= A_ANCH / 2) return;
    int a0 = g * 2;
    const float* base = preds + ((size_t)b * NROWS + 4) * A_ANCH + a0;
    float2 best = *(const float2*)base;
    int bc0 = 0, bc1 = 0;
#pragma unroll 8
    for (int c = 1; c < NC; ++c) {
        float2 v = *(const float2*)(base + (size_t)c * A_ANCH);
        if (v.x > best.x) { best.x = v.x; bc0 = c; }   // strict > = first-max argmax
        if (v.y > best.y) { best.y = v.y; bc1 = c; }
    }
    float s0 = (best.x > CONF_T) ? best.x : 0.0f;
    float s1 = (best.y > CONF_T) ? best.y : 0.0f;
    ulonglong2 kk;
    kk.x = ((u64)__float_as_uint(s0) << 32) | ((u64)(16383 - a0) << 7) | (u64)bc0;
    kk.y = ((u64)__float_as_uint(s1) << 32) | ((u64)(16383 - (a0 + 1)) << 7) | (u64)bc1;
    *(ulonglong2*)(keys + (size_t)b * A_ANCH + a0) = kk;
}

__device__ __forceinline__ float iou_f(float ix1, float iy1, float ix2, float iy2, float iar,
                                       float jx1, float jy1, float jx2, float jy2, float jar) {
    float lx = fmaxf(ix1, jx1), ly = fmaxf(iy1, jy1);
    float rx = fminf(ix2, jx2), ry = fminf(iy2, jy2);
    float ww = fmaxf(__fsub_rn(rx, lx), 0.0f);
    float hh = fmaxf(__fsub_rn(ry, ly), 0.0f);
    float inter = __fmul_rn(ww, hh);
    float den = __fadd_rn(__fsub_rn(__fadd_rn(iar, jar), inter), 1e-7f);
    return __fdiv_rn(inter, den);
}

// adaptive wave histogram add: 1 atomic for the dominant bin, per-lane for stragglers
__device__ __forceinline__ void hadd(u32* h, u32 bin, bool m, int lane) {
    u64 act = __ballot(m);
    if (act == 0) return;
    int fl = __ffsll((unsigned long long)act) - 1;
    u32 fb = __shfl(bin, fl);
    u64 same = __ballot(m && (bin == fb));
    if (lane == fl) atomicAdd(&h[fb], (u32)__popcll(same));
    if (m && (bin != fb)) atomicAdd(&h[bin], 1u);
}

// bitonic compare-exchange step on element idx, partner idx^stride (in-wave, stride<=32)
__device__ __forceinline__ u64 bstep(u64 v, u32 idx, u32 size, u32 stride) {
    u64 v2 = __shfl_xor((unsigned long long)v, (int)stride, 64);
    bool keep_big = (((idx & stride) == 0) == ((idx & size) == 0));
    return ((v > v2) == keep_big) ? v : v2;
}

// ---------------- Kernel 2: top-1024 select + sort + greedy NMS + emit ----------------
__global__ __launch_bounds__(512) void yolo_nms_kernel(const float* __restrict__ preds,
                                                       const u64* __restrict__ keys,
                                                       float* __restrict__ out) {
    const int b = blockIdx.x;
    const int tid = threadIdx.x;
    const int lane = tid & 63;
    const int wid = tid >> 6;    // 0..7

    __shared__ u32 sc[A_ANCH];           // 33600 B; later overlaid with box arrays
    __shared__ u64 skey[KCAND];          // 8192 B
    __shared__ u32 histw[8 * 257];       // padded rows -> dominant bin spreads over banks
    __shared__ u32 hist[256];
    union OvU {
        struct { u32 eqw[264]; u32 wpre[264]; } pre;
        struct {
            u64 rows[64];
            int keptlist[364];
            float kx1[364], ky1[364], kx2[364], ky2[364], kar[364];
            u32 kcls[364];
        } post;
    };
    __shared__ OvU ov;
    __shared__ u32 s_scal[4];            // 0: radix prefix/P, 1: k-remaining, 2: compact cnt
    __shared__ u32 s_csupp[2];
    __shared__ u32 s_nkept;

    const u64* kb = keys + (size_t)b * A_ANCH;

    for (int i = tid; i < 8 * 257; i += 512) histw[i] = 0;
    if (tid == 0) { s_scal[0] = 0; s_scal[1] = KCAND; s_scal[2] = 0; s_csupp[0] = 0; s_csupp[1] = 0; s_nkept = 0; }

    // pipelined load of score bits into regs, then LDS
    u32 vals[17];
#pragma unroll
    for (int it = 0; it < 17; ++it) {
        int a = tid + it * 512;
        vals[it] = (a < A_ANCH) ? (u32)(kb[a] >> 32) : 0u;
    }
#pragma unroll
    for (int it = 0; it < 17; ++it) {
        int a = tid + it * 512;
        if (a < A_ANCH) sc[a] = vals[it];
    }
    __syncthreads();

    // ---- radix select: P = 1024th-largest score bits (4 x 8-bit passes) ----
    u32* hw = histw + wid * 257;
    for (int p = 0; p < 4; ++p) {
        if (p == 0) {
#pragma unroll
            for (int it = 0; it < 17; ++it) {
                int a = tid + it * 512;
                hadd(hw, vals[it] >> 24, a < A_ANCH, lane);
            }
        } else {
            for (int i = tid; i < 8 * 257; i += 512) histw[i] = 0;
            __syncthreads();
            u32 prefix = s_scal[0];
            int shift = 24 - 8 * p;
            for (int it = 0; it < 17; ++it) {
                int a = tid + it * 512;
                u32 v = (a < A_ANCH) ? sc[a] : 0u;
                bool m = (a < A_ANCH) && ((v >> (shift + 8)) == prefix);
                hadd(hw, (v >> shift) & 255u, m, lane);
            }
        }
        __syncthreads();
        if (tid < 256) {
            u32 s = 0;
#pragma unroll
            for (int w = 0; w < 8; ++w) s += histw[w * 257 + tid];
            hist[tid] = s;
        }
        __syncthreads();
        if (wid == 0) {
            u32 g[4], loc = 0;
#pragma unroll
            for (int q = 0; q < 4; ++q) { g[q] = hist[255 - (lane * 4 + q)]; loc += g[q]; }
            u32 pre = loc;
#pragma unroll
            for (int off = 1; off < 64; off <<= 1) {
                u32 o = __shfl_up(pre, off);
                if (lane >= off) pre += o;
            }
            u32 run = pre - loc;
            u32 rem = s_scal[1];
            u32 pfx = s_scal[0];
#pragma unroll
            for (int q = 0; q < 4; ++q) {
                int d = 255 - (lane * 4 + q);
                if (run < rem && rem <= run + g[q]) {
                    s_scal[0] = (pfx << 8) | (u32)d;
                    s_scal[1] = rem - run;
                }
                run += g[q];
            }
        }
        __syncthreads();
    }
    const u32 P = s_scal[0];
    const u32 tEq = s_scal[1];   // take tEq lowest-index elements among score==P

    // ---- tie handling ----
    if (tid < 264) ov.pre.eqw[tid] = 0;
    __syncthreads();
    for (int it = 0; it < 17; ++it) {
        int a = tid + it * 512;
        if (a < A_ANCH && sc[a] == P) atomicOr(&ov.pre.eqw[a >> 5], 1u << (a & 31));
    }
    __syncthreads();
    if (wid == 0) {
        u32 cnt[5], loc = 0;
#pragma unroll
        for (int q = 0; q < 5; ++q) {
            int w2 = lane * 5 + q;
            u32 e = (w2 < 264) ? ov.pre.eqw[w2] : 0u;
            cnt[q] = (u32)__popc(e); loc += cnt[q];
        }
        u32 pre = loc;
#pragma unroll
        for (int off = 1; off < 64; off <<= 1) {
            u32 o = __shfl_up(pre, off);
            if (lane >= off) pre += o;
        }
        u32 run = pre - loc;
#pragma unroll
        for (int q = 0; q < 5; ++q) {
            int w2 = lane * 5 + q;
            if (w2 < 264) ov.pre.wpre[w2] = run;
            run += cnt[q];
        }
    }
    __syncthreads();

    // ---- compaction of exactly 1024 keys ----
    for (int it = 0; it < 17; ++it) {
        int a = tid + it * 512;
        if (a < A_ANCH) {
            u32 v = sc[a];
            bool take = v > P;
            if (!take && v == P) {
                u32 r = ov.pre.wpre[a >> 5] + (u32)__popc(ov.pre.eqw[a >> 5] & ((1u << (a & 31)) - 1u));
                take = (r < tEq);
            }
            if (take) {
                u32 pos = atomicAdd(&s_scal[2], 1u);
                skey[pos] = kb[a];
            }
        }
    }
    __syncthreads();

    // ---- hybrid bitonic sort, descending: strides<=32 in registers, >=64 in LDS ----
    {
        u64 vA = skey[tid], vB = skey[tid + 512];
        const u32 iA = (u32)tid, iB = (u32)tid + 512;
#pragma unroll
        for (u32 size = 2; size <= 64; size <<= 1) {
#pragma unroll
            for (u32 stride = size >> 1; stride >= 1; stride >>= 1) {
                vA = bstep(vA, iA, size, stride);
                vB = bstep(vB, iB, size, stride);
            }
        }
        skey[tid] = vA; skey[tid + 512] = vB;
        __syncthreads();
        for (u32 size = 128; size <= 1024; size <<= 1) {
            for (u32 stride = size >> 1; stride >= 64; stride >>= 1) {
                u32 i1 = ((tid & ~(int)(stride - 1)) << 1) | (tid & (stride - 1));
                u32 i2 = i1 + stride;
                bool desc = ((i1 & size) == 0);
                u64 x = skey[i1], y = skey[i2];
                if ((x < y) == desc) { skey[i1] = y; skey[i2] = x; }
                __syncthreads();
            }
            vA = skey[tid]; vB = skey[tid + 512];
#pragma unroll
            for (u32 stride = 32; stride >= 1; stride >>= 1) {
                vA = bstep(vA, iA, size, stride);
                vB = bstep(vB, iB, size, stride);
            }
            skey[tid] = vA; skey[tid + 512] = vB;
            __syncthreads();
        }
    }

    // ---- per-candidate offset boxes (overlay onto sc region) ----
    float* BX1 = (float*)sc;
    float* BY1 = BX1 + KCAND;
    float* BX2 = BX1 + 2 * KCAND;
    float* BY2 = BX1 + 3 * KCAND;
    float* BAR = BX1 + 4 * KCAND;
#pragma unroll
    for (int q = 0; q < 2; ++q) {
        int t = tid + q * 512;
        u64 key = skey[t];
        int cls = (int)(key & 127u);
        int idx = 16383 - (int)((key >> 7) & 16383u);
        const float* pb = preds + (size_t)b * NROWS * A_ANCH + idx;
        float x = pb[0];
        float y = pb[A_ANCH];
        float w = pb[2 * A_ANCH];
        float h = pb[3 * A_ANCH];
        float hw = __fmul_rn(w, 0.5f), hh = __fmul_rn(h, 0.5f);
        float x1 = __fsub_rn(x, hw), x2 = __fadd_rn(x, hw);
        float y1 = __fsub_rn(y, hh), y2 = __fadd_rn(y, hh);
        float off = __fmul_rn((float)cls, MAX_WH);
        float bx1 = __fadd_rn(x1, off), bx2 = __fadd_rn(x2, off);
        float by1 = __fadd_rn(y1, off), by2 = __fadd_rn(y2, off);
        BX1[t] = bx1; BY1[t] = by1; BX2[t] = bx2; BY2[t] = by2;
        BAR[t] = __fmul_rn(__fsub_rn(bx2, bx1), __fsub_rn(by2, by1));  // area of OFFSET box, as reference
    }
    __syncthreads();

    // ---- greedy NMS: 16 chunks of 64 ----
    for (int c = 0; c < KCAND / 64; ++c) {
        int j = c * 64 + lane;
        u64 keyj = skey[j];
        float scj = __uint_as_float((u32)(keyj >> 32));
        u32 clsj = (u32)(keyj & 127u);
        float jx1 = BX1[j], jy1 = BY1[j], jx2 = BX2[j], jy2 = BY2[j], jar = BAR[j];

        // Phase A: this chunk's 64 candidates vs compact kept list (8 waves strided, breakless)
        u32 nk = s_nkept;
        bool suppbit = false;
        for (u32 k = wid; k < nk; k += 8) {
            bool cm = (ov.post.kcls[k] == clsj);
            if (__ballot(cm)) {     // cross-class IoU is exactly 0 (7680 offset) -> skip
                float iou = iou_f(ov.post.kx1[k], ov.post.ky1[k], ov.post.kx2[k], ov.post.ky2[k],
                                  ov.post.kar[k], jx1, jy1, jx2, jy2, jar);
                suppbit |= (cm && (iou > IOU_THR));
            }
        }
        u64 bm = __ballot(suppbit);
        if (bm && lane == 0) {
            atomicOr(&s_csupp[0], (u32)bm);
            atomicOr(&s_csupp[1], (u32)(bm >> 32));
        }

        // Phase B: in-chunk 64x64 suppression matrix, 8 rows per wave
#pragma unroll
        for (int p2 = 0; p2 < 8; ++p2) {
            int i = p2 * 8 + wid;
            int ci = c * 64 + i;
            u32 clsi = (u32)(skey[ci] & 127u);
            u64 m = 0;
            if (__ballot(clsi == clsj)) {
                float iou = iou_f(BX1[ci], BY1[ci], BX2[ci], BY2[ci], BAR[ci],
                                  jx1, jy1, jx2, jy2, jar);
                m = __ballot((lane > i) && (iou > IOU_THR));
            }
            if (lane == 0) ov.post.rows[i] = m;
        }
        __syncthreads();

        // Phase C: wave-0 scalar greedy recurrence (readlane -> SGPR chain)
        if (wid == 0) {
            u64 row = ov.post.rows[lane];
            u32 rlo = (u32)row, rhi = (u32)(row >> 32);
            u64 csupp = (((u64)s_csupp[1]) << 32) | (u64)s_csupp[0];
            u64 valid = __ballot(scj > CONF_T) & ~csupp;
            u64 supp = 0, keep = 0;
#pragma unroll
            for (int i = 0; i < 64; ++i) {
                u64 ri = (((u64)(u32)__builtin_amdgcn_readlane((int)rhi, i)) << 32) |
                         (u64)(u32)__builtin_amdgcn_readlane((int)rlo, i);
                bool ki = (((valid & ~supp) >> i) & 1ull) != 0;
                if (ki) { keep |= (1ull << i); supp |= ri; }
            }
            u32 base = s_nkept;
            if ((keep >> lane) & 1ull) {
                u32 slot = base + (u32)__popcll(keep & ((1ull << lane) - 1ull));
                ov.post.keptlist[slot] = j;
                ov.post.kx1[slot] = jx1; ov.post.ky1[slot] = jy1;
                ov.post.kx2[slot] = jx2; ov.post.ky2[slot] = jy2;
                ov.post.kar[slot] = jar; ov.post.kcls[slot] = clsj;
            }
            if (lane == 0) {
                s_nkept = base + (u32)__popcll(keep);
                s_csupp[0] = 0; s_csupp[1] = 0;
            }
        }
        __syncthreads();
        if (s_nkept >= MAX_DET) break;   // suppression flows only forward; first 300 fixed
    }

    // ---- emit output rows ----
    if (tid < MAX_DET) {
        u32 nk = s_nkept;
        float row[6];
        int t = (tid < (int)(nk < MAX_DET ? nk : MAX_DET)) ? ov.post.keptlist[tid] : -1;
        if (t >= 0) {
            u64 key = skey[t];
            float score = __uint_as_float((u32)(key >> 32));
            int cls = (int)(key & 127u);
            int idx = 16383 - (int)((key >> 7) & 16383u);
            const float* pb = preds + (size_t)b * NROWS * A_ANCH + idx;
            float x = pb[0], y = pb[A_ANCH], w = pb[2 * A_ANCH], h = pb[3 * A_ANCH];
            float hw = __fmul_rn(w, 0.5f), hh = __fmul_rn(h, 0.5f);
            row[0] = __fsub_rn(x, hw);
            row[1] = __fsub_rn(y, hh);
            row[2] = __fadd_rn(x, hw);
            row[3] = __fadd_rn(y, hh);
            row[4] = score;
            row[5] = (float)cls;
        } else {
            row[0] = row[1] = row[2] = row[3] = row[4] = row[5] = (float)NC;
        }
        float* o = out + ((size_t)b * MAX_DET + tid) * 6;
#pragma unroll
        for (int q = 0; q < 6; ++q) o[q] = row[q];
    }
}

extern "C" void kernel_launch(void* const* d_in, const int* in_sizes, int n_in,
                              void* d_out, int out_size, void* d_ws, size_t ws_size,
                              hipStream_t stream) {
    const float* preds = (const float*)d_in[0];
    float* out = (float*)d_out;
    u64* keys = (u64*)d_ws;   // B * 8400 * 8 bytes ~= 2.1 MB
    int B = in_sizes[0] / (NROWS * A_ANCH);
    yolo_conf_kernel<<<dim3(B * 9), dim3(512), 0, stream>>>(preds, keys);
    yolo_nms_kernel<<<dim3(B), dim3(512), 0, stream>>>(preds, keys, out);
}